// Round 9
// baseline (1178.602 us; speedup 1.0000x reference)
//
#include <hip/hip_runtime.h>

// SigWassersteinMetric: depth-4 path signature, C=10, T=256.
//   original: (4096, 256, 10) f32; generated: (1024, 256, 10) f32; sample_idx: (1024,)
//
// ROUND-23: R17 hot loop (256 thr, third-time-confirmed local optimum) +
// atomic-replica accumulation as PRIMARY (kills the 180MB ws round-trip).
//   - R22 post-mortem: 128-thr amortization FAILED (VGPR 88 -> 4 waves/SIMD
//     cap, occupancy 20%, accum 200us; WRITE 165MB from bad coalescing), but
//     the 3-dispatch structure won (total 279 = best). Loop reverts to R17.
//   - Ledger: ~74us residual = sum(91MB read) 15 + sumsq 3 + launch/drain ~55.
//   - This round: accum blocks atomicAdd signed signatures directly into 64
//     replicas (2.8MB, L2-resident; 32 blocks/replica, low contention; native
//     device-scope f32 atomics). One small reduce (44 blocks) finishes.
//     Traffic 182MB -> ~6MB. Dispatches: memset(2.8MB) + accum + reduce.
//   - Prediction: accum ~190-200, VGPR ~50, WRITE 165->15MB, total 235-255.
//     Failure: atomic serialization (accum >=230) -> revert to fused-sum-B.
//
// Horner-factored Chen step (verified rounds 2/4-13):
//   A2 = S2 + (S1 + v/4) (x) v/3 ;  B2 = S2 + (S1 + v/3) (x) v/2
//   A3 = S3 + A2 (x) v/2 ;  S4' = S4 + A3 (x) v ;  S3' = S3 + B2 (x) v
//   S2' = S2 + (S1 + v/2) (x) v ;  S1 closed-form in epilogue.
#define T_LEN 256
#define C_DIM 10
#define NSTEP 255
#define BSZ   1024
#define NPAIR 1024
#define D1 10
#define D2 100
#define D3 1000
#define DTOT 11110
#define PATH_ELEMS (T_LEN * C_DIM)   // 2560
#define DX_ELEMS (NSTEP * C_DIM)     // 2550
#define DXROW 12                     // padded dx row stride (48 B, 16B-aligned)

typedef float f32x2 __attribute__((ext_vector_type(2)));
typedef float f32x4 __attribute__((ext_vector_type(4)));

// d += bcast(a.lo) * b
#define PK_FMA_B0(d, a, b) \
    asm("v_pk_fma_f32 %0, %1, %2, %0 op_sel:[0,0,0] op_sel_hi:[0,1,1]" \
        : "+v"(d) : "v"(a), "v"(b))
// d += bcast(a.hi) * b
#define PK_FMA_B1(d, a, b) \
    asm("v_pk_fma_f32 %0, %1, %2, %0 op_sel:[1,0,0] op_sel_hi:[1,1,1]" \
        : "+v"(d) : "v"(a), "v"(b))
// d = bcast(a.lo) * b + c
#define PK_FMA_B0N(d, a, b, c) \
    asm("v_pk_fma_f32 %0, %1, %2, %3 op_sel:[0,0,0] op_sel_hi:[0,1,1]" \
        : "=v"(d) : "v"(a), "v"(b), "v"(c))
// d = bcast(a.hi) * b + c
#define PK_FMA_B1N(d, a, b, c) \
    asm("v_pk_fma_f32 %0, %1, %2, %3 op_sel:[1,0,0] op_sel_hi:[1,1,1]" \
        : "=v"(d) : "v"(a), "v"(b), "v"(c))
// d = a * bcast(b.lo) + c   (src1 broadcast)
#define PK_FMA_S1B0N(d, a, b, c) \
    asm("v_pk_fma_f32 %0, %1, %2, %3 op_sel:[0,0,0] op_sel_hi:[1,0,1]" \
        : "=v"(d) : "v"(a), "v"(b), "v"(c))
// d = a * bcast(b.hi) + c
#define PK_FMA_S1B1N(d, a, b, c) \
    asm("v_pk_fma_f32 %0, %1, %2, %3 op_sel:[0,1,0] op_sel_hi:[1,1,1]" \
        : "=v"(d) : "v"(a), "v"(b), "v"(c))
// d += a * bcast(b.lo)
#define PK_FMA_S1B0(d, a, b) \
    asm("v_pk_fma_f32 %0, %1, %2, %0 op_sel:[0,0,0] op_sel_hi:[1,0,1]" \
        : "+v"(d) : "v"(a), "v"(b))
// d += a * bcast(b.hi)
#define PK_FMA_S1B1(d, a, b) \
    asm("v_pk_fma_f32 %0, %1, %2, %0 op_sel:[0,1,0] op_sel_hi:[1,1,1]" \
        : "+v"(d) : "v"(a), "v"(b))
// d = a * 0.5 (both halves)
#define PK_MUL_HALF(d, a) \
    asm("v_pk_mul_f32 %0, %1, 0.5 op_sel:[0,0] op_sel_hi:[1,0]" \
        : "=v"(d) : "v"(a))

__global__ __launch_bounds__(256)
void sig_accum_kernel(
    const float* __restrict__ original,
    const float* __restrict__ generated,
    const int* __restrict__ sample_idx,
    float* __restrict__ ws, int nrep)
{
    const int tid  = threadIdx.x;
    const int bp   = blockIdx.x;         // 0 .. 2*NPAIR-1
    const int b    = bp >> 1;            // pair index
    const int pass = bp & 1;             // 0 = generated (-), 1 = original (+)
    const float sgn = pass ? 1.0f : -1.0f;

    __shared__ __align__(16) float s_dx[NSTEP * DXROW];  // 12240 B

    const float* path = pass
        ? original + (size_t)sample_idx[b] * PATH_ELEMS
        : generated + (size_t)b * PATH_ELEMS;

    for (int idx = tid; idx < DX_ELEMS; idx += 256) {
        int t = idx / C_DIM, c = idx - t * C_DIM;
        s_dx[t * DXROW + c] = path[idx + C_DIM] - path[idx];
    }
    __syncthreads();

    const int mbase = 2 * tid;               // valid tid<250
    const int k0  = mbase / 100;             // 0..4
    const int ij0 = mbase - k0 * 100;        // even
    const int ia  = ij0 / 10;
    const int j0  = ij0 - ia * 10;           // even -> (j0, j0+1) same decade

    float s1a = 0.0f;
    f32x2 s2p = {0.0f, 0.0f};                 // (q0, q1)
    f32x2 s3p[2] = {{0.0f, 0.0f}, {0.0f, 0.0f}};  // [0]=(q0,q1)@k0, [1]=@k1
    f32x2 acc2[4][5];                         // [0]=q0k0 [1]=q1k0 [2]=q0k1 [3]=q1k1
    #pragma unroll
    for (int r = 0; r < 4; ++r)
        #pragma unroll
        for (int i = 0; i < 5; ++i) acc2[r][i] = (f32x2){0.0f, 0.0f};

    if (tid < 250) {
        const float* vrow = s_dx;
        #pragma unroll 2
        for (int t = 0; t < NSTEP; ++t, vrow += DXROW) {
            const f32x4 va = *(const f32x4*)(vrow);        // v0..v3 (uniform)
            const f32x4 vb = *(const f32x4*)(vrow + 4);    // v4..v7 (uniform)
            const f32x2 vc = *(const f32x2*)(vrow + 8);    // v8,v9  (uniform)
            const f32x2 vjp = *(const f32x2*)(vrow + j0);  // vj for q0,q1
            const float via = vrow[ia];
            f32x2 vkp;
            vkp.x = vrow[k0];
            vkp.y = vrow[k0 + 5];

            const f32x2 vv2[5] = {va.xy, va.zw, vb.xy, vb.zw, vc};

            // scalar prefix terms
            const float t3  = fmaf(via, 0.5f, s1a);
            const float t1b = fmaf(via, 0.25f, s1a) * (1.0f / 3.0f);
            const float t2b = fmaf(via, (1.0f / 3.0f), s1a) * 0.5f;
            f32x2 pA; pA.x = t1b; pA.y = t2b;
            f32x2 pT; pT.x = t3;  pT.y = t3;

            f32x2 vkhp;                       // (vk0*0.5, vk1*0.5)
            PK_MUL_HALF(vkhp, vkp);

            // level 2 (q-pairs)
            f32x2 a2p, b2p;
            PK_FMA_B0N(a2p, pA, vjp, s2p);    // a2_q = t1b*vj_q + s2_q
            PK_FMA_B1N(b2p, pA, vjp, s2p);    // b2_q = t2b*vj_q + s2_q
            PK_FMA_B0(s2p, pT, vjp);          // s2_q += t3*vj_q

            // level 3 (q-pairs, k-channel broadcast from vkp/vkhp halves)
            f32x2 a3xp, a3yp;
            PK_FMA_S1B0N(a3xp, a2p, vkhp, s3p[0]);  // a3_q@k0
            PK_FMA_S1B1N(a3yp, a2p, vkhp, s3p[1]);  // a3_q@k1
            PK_FMA_S1B0(s3p[0], b2p, vkp);          // s3_q@k0 += b2_q*vk0
            PK_FMA_S1B1(s3p[1], b2p, vkp);          // s3_q@k1 += b2_q*vk1

            // level 4: 20 pk-FMAs (a3 broadcast from pair halves)
            #pragma unroll
            for (int i = 0; i < 5; ++i) {
                PK_FMA_B0(acc2[0][i], a3xp, vv2[i]);
                PK_FMA_B1(acc2[1][i], a3xp, vv2[i]);
                PK_FMA_B0(acc2[2][i], a3yp, vv2[i]);
                PK_FMA_B1(acc2[3][i], a3yp, vv2[i]);
            }
            s1a += via;
        }
    }

    // ---- Epilogue: signed atomic accumulation into replica b % nrep ----
    float* base = ws + (size_t)(b % nrep) * DTOT;
    if (tid < D1)
        atomicAdd(&base[tid],
                  sgn * (path[(T_LEN - 1) * C_DIM + tid] - path[tid]));
    if (tid < 50) {           // k0 == 0 threads own ij0 = 2*tid
        atomicAdd(&base[D1 + ij0],     sgn * s2p[0]);
        atomicAdd(&base[D1 + ij0 + 1], sgn * s2p[1]);
    }
    if (tid < 250) {
        #pragma unroll
        for (int ch = 0; ch < 2; ++ch) {      // ch=0 -> k0, ch=1 -> k0+5
            const int kk = k0 + 5 * ch;
            #pragma unroll
            for (int q = 0; q < 2; ++q) {
                const int idx3 = (ij0 + q) * 10 + kk;
                atomicAdd(&base[D1 + D2 + idx3], sgn * s3p[ch][q]);
                #pragma unroll
                for (int l = 0; l < 10; ++l)
                    atomicAdd(&base[D1 + D2 + D3 + idx3 * 10 + l],
                              sgn * acc2[ch][q * (ch == 0 ? 1 : 1) + 0][0] * 0.0f
                              + sgn * acc2[ch * 2 + q][l >> 1][l & 1]);
            }
        }
    }
}

// Final reduce: sum nrep replica rows, square, norm. 44 blocks.
__global__ __launch_bounds__(256) void sig_reduce_kernel(
    const float* __restrict__ ws, int nrows, float* __restrict__ sumsq,
    unsigned int* __restrict__ counter, float* __restrict__ out, int nblocks)
{
    const int d = blockIdx.x * 256 + threadIdx.x;
    float s = 0.0f;
    if (d < DTOT) {
        for (int r = 0; r < nrows; ++r) s += ws[(size_t)r * DTOT + d];
        s = s * s;
    }
    for (int off = 32; off > 0; off >>= 1) s += __shfl_down(s, off, 64);
    __shared__ float red[4];
    __shared__ unsigned int lastflag;
    if ((threadIdx.x & 63) == 0) red[threadIdx.x >> 6] = s;
    __syncthreads();
    if (threadIdx.x == 0) {
        atomicAdd(sumsq, red[0] + red[1] + red[2] + red[3]);
        __threadfence();
        lastflag = (atomicAdd(counter, 1u) == (unsigned int)(nblocks - 1));
    }
    __syncthreads();
    if (threadIdx.x == 0 && lastflag) {
        __threadfence();
        out[0] = sqrtf(*(volatile float*)sumsq) * (1.0f / (float)BSZ);
    }
}

extern "C" void kernel_launch(void* const* d_in, const int* in_sizes, int n_in,
                              void* d_out, int out_size, void* d_ws, size_t ws_size,
                              hipStream_t stream) {
    const float* original   = (const float*)d_in[0];
    const float* generated  = (const float*)d_in[1];
    const int*   sample_idx = (const int*)d_in[2];
    float* out = (float*)d_out;
    float* ws  = (float*)d_ws;

    // Layout: replicas [0, nrep*DTOT), sumsq [+1), counter [+1)
    int nrep = 1;
    if (ws_size >= ((size_t)64 * DTOT + 2) * sizeof(float)) nrep = 64;
    else if (ws_size >= ((size_t)8 * DTOT + 2) * sizeof(float)) nrep = 8;

    float* sumsq = ws + (size_t)nrep * DTOT;
    unsigned int* counter = (unsigned int*)(sumsq + 1);
    hipMemsetAsync(ws, 0, ((size_t)nrep * DTOT + 2) * sizeof(float), stream);
    sig_accum_kernel<<<2 * NPAIR, 256, 0, stream>>>(original, generated,
                                                    sample_idx, ws, nrep);
    const int nb2 = (DTOT + 255) / 256;
    sig_reduce_kernel<<<nb2, 256, 0, stream>>>(ws, nrep, sumsq, counter, out, nb2);
}

// Round 10
// 301.965 us; speedup vs baseline: 3.9031x; 3.9031x over previous
//
#include <hip/hip_runtime.h>

// SigWassersteinMetric: depth-4 path signature, C=10, T=256.
//   original: (4096, 256, 10) f32; generated: (1024, 256, 10) f32; sample_idx: (1024,)
//
// ROUND-24: all verified-good pieces, 2 dispatches.
//   - R23 post-mortem: bulk atomic accumulation = 28.7M coherence-point RMWs
//     -> 694MB HBM write, 1089us. NEVER bulk-atomic. Rows + reduction wins.
//   - accum = exact R21 config (R17 loop, 256thr, store rows, block0 inits
//     accvec+counter): measured 184.9-190.5us, VGPR 44.
//   - Fused sum+norm WITHOUT __threadfence (R21's fused version died on
//     1408 block-wide fences): __syncthreads() already drains vmcnt(0)
//     (compiler emits full s_waitcnt before s_barrier), so each block's
//     accvec atomicAdds are complete at the coherence point BEFORE thread 0
//     bumps the counter. Last block re-reads accvec via atomic-reads
//     (atomicAdd(p,0.0f) -- L1-bypassing, coherent) and writes the norm.
//   - Dispatches 3 -> 2; each boundary has measured ~15-20us.
//   - Prediction: accum ~187, sumred ~20, total ~240-260.
//
// Horner-factored Chen step (verified rounds 2/4-13):
//   A2 = S2 + (S1 + v/4) (x) v/3 ;  B2 = S2 + (S1 + v/3) (x) v/2
//   A3 = S3 + A2 (x) v/2 ;  S4' = S4 + A3 (x) v ;  S3' = S3 + B2 (x) v
//   S2' = S2 + (S1 + v/2) (x) v ;  S1 closed-form in epilogue.
#define T_LEN 256
#define C_DIM 10
#define NSTEP 255
#define BSZ   1024
#define NPAIR 1024
#define D1 10
#define D2 100
#define D3 1000
#define DTOT 11110
#define PATH_ELEMS (T_LEN * C_DIM)   // 2560
#define DX_ELEMS (NSTEP * C_DIM)     // 2550
#define DXROW 12                     // padded dx row stride (48 B, 16B-aligned)

typedef float f32x2 __attribute__((ext_vector_type(2)));
typedef float f32x4 __attribute__((ext_vector_type(4)));

// d += bcast(a.lo) * b
#define PK_FMA_B0(d, a, b) \
    asm("v_pk_fma_f32 %0, %1, %2, %0 op_sel:[0,0,0] op_sel_hi:[0,1,1]" \
        : "+v"(d) : "v"(a), "v"(b))
// d += bcast(a.hi) * b
#define PK_FMA_B1(d, a, b) \
    asm("v_pk_fma_f32 %0, %1, %2, %0 op_sel:[1,0,0] op_sel_hi:[1,1,1]" \
        : "+v"(d) : "v"(a), "v"(b))
// d = bcast(a.lo) * b + c
#define PK_FMA_B0N(d, a, b, c) \
    asm("v_pk_fma_f32 %0, %1, %2, %3 op_sel:[0,0,0] op_sel_hi:[0,1,1]" \
        : "=v"(d) : "v"(a), "v"(b), "v"(c))
// d = bcast(a.hi) * b + c
#define PK_FMA_B1N(d, a, b, c) \
    asm("v_pk_fma_f32 %0, %1, %2, %3 op_sel:[1,0,0] op_sel_hi:[1,1,1]" \
        : "=v"(d) : "v"(a), "v"(b), "v"(c))
// d = a * bcast(b.lo) + c   (src1 broadcast)
#define PK_FMA_S1B0N(d, a, b, c) \
    asm("v_pk_fma_f32 %0, %1, %2, %3 op_sel:[0,0,0] op_sel_hi:[1,0,1]" \
        : "=v"(d) : "v"(a), "v"(b), "v"(c))
// d = a * bcast(b.hi) + c
#define PK_FMA_S1B1N(d, a, b, c) \
    asm("v_pk_fma_f32 %0, %1, %2, %3 op_sel:[0,1,0] op_sel_hi:[1,1,1]" \
        : "=v"(d) : "v"(a), "v"(b), "v"(c))
// d += a * bcast(b.lo)
#define PK_FMA_S1B0(d, a, b) \
    asm("v_pk_fma_f32 %0, %1, %2, %0 op_sel:[0,0,0] op_sel_hi:[1,0,1]" \
        : "+v"(d) : "v"(a), "v"(b))
// d += a * bcast(b.hi)
#define PK_FMA_S1B1(d, a, b) \
    asm("v_pk_fma_f32 %0, %1, %2, %0 op_sel:[0,1,0] op_sel_hi:[1,1,1]" \
        : "+v"(d) : "v"(a), "v"(b))
// d = a * 0.5 (both halves)
#define PK_MUL_HALF(d, a) \
    asm("v_pk_mul_f32 %0, %1, 0.5 op_sel:[0,0] op_sel_hi:[1,0]" \
        : "=v"(d) : "v"(a))

__global__ __launch_bounds__(256)
void sig_accum_kernel(
    const float* __restrict__ original,
    const float* __restrict__ generated,
    const int* __restrict__ sample_idx,
    float* __restrict__ ws,
    float* __restrict__ accinit,   // non-null: block 0 zeroes DTOT+2 floats
    int nrep, int store_mode)
{
    const int tid  = threadIdx.x;
    const int bp   = blockIdx.x;         // 0 .. 2*NPAIR-1
    const int b    = bp >> 1;            // pair index
    const int pass = bp & 1;             // 0 = generated (-), 1 = original (+)
    const float sgn = pass ? 1.0f : -1.0f;

    __shared__ __align__(16) float s_dx[NSTEP * DXROW];  // 12240 B

    if (accinit != nullptr && bp == 0) {
        for (int i = tid; i < DTOT + 2; i += 256) accinit[i] = 0.0f;
    }

    const float* path = pass
        ? original + (size_t)sample_idx[b] * PATH_ELEMS
        : generated + (size_t)b * PATH_ELEMS;

    for (int idx = tid; idx < DX_ELEMS; idx += 256) {
        int t = idx / C_DIM, c = idx - t * C_DIM;
        s_dx[t * DXROW + c] = path[idx + C_DIM] - path[idx];
    }
    __syncthreads();

    const int mbase = 2 * tid;               // valid tid<250
    const int k0  = mbase / 100;             // 0..4
    const int ij0 = mbase - k0 * 100;        // even
    const int ia  = ij0 / 10;
    const int j0  = ij0 - ia * 10;           // even -> (j0, j0+1) same decade

    float s1a = 0.0f;
    f32x2 s2p = {0.0f, 0.0f};                 // (q0, q1)
    f32x2 s3p[2] = {{0.0f, 0.0f}, {0.0f, 0.0f}};  // [0]=(q0,q1)@k0, [1]=@k1
    f32x2 acc2[4][5];                         // [0]=q0k0 [1]=q1k0 [2]=q0k1 [3]=q1k1
    #pragma unroll
    for (int r = 0; r < 4; ++r)
        #pragma unroll
        for (int i = 0; i < 5; ++i) acc2[r][i] = (f32x2){0.0f, 0.0f};

    if (tid < 250) {
        const float* vrow = s_dx;
        #pragma unroll 2
        for (int t = 0; t < NSTEP; ++t, vrow += DXROW) {
            const f32x4 va = *(const f32x4*)(vrow);        // v0..v3 (uniform)
            const f32x4 vb = *(const f32x4*)(vrow + 4);    // v4..v7 (uniform)
            const f32x2 vc = *(const f32x2*)(vrow + 8);    // v8,v9  (uniform)
            const f32x2 vjp = *(const f32x2*)(vrow + j0);  // vj for q0,q1
            const float via = vrow[ia];
            f32x2 vkp;
            vkp.x = vrow[k0];
            vkp.y = vrow[k0 + 5];

            const f32x2 vv2[5] = {va.xy, va.zw, vb.xy, vb.zw, vc};

            // scalar prefix terms
            const float t3  = fmaf(via, 0.5f, s1a);
            const float t1b = fmaf(via, 0.25f, s1a) * (1.0f / 3.0f);
            const float t2b = fmaf(via, (1.0f / 3.0f), s1a) * 0.5f;
            f32x2 pA; pA.x = t1b; pA.y = t2b;
            f32x2 pT; pT.x = t3;  pT.y = t3;

            f32x2 vkhp;                       // (vk0*0.5, vk1*0.5)
            PK_MUL_HALF(vkhp, vkp);

            // level 2 (q-pairs)
            f32x2 a2p, b2p;
            PK_FMA_B0N(a2p, pA, vjp, s2p);    // a2_q = t1b*vj_q + s2_q
            PK_FMA_B1N(b2p, pA, vjp, s2p);    // b2_q = t2b*vj_q + s2_q
            PK_FMA_B0(s2p, pT, vjp);          // s2_q += t3*vj_q

            // level 3 (q-pairs, k-channel broadcast from vkp/vkhp halves)
            f32x2 a3xp, a3yp;
            PK_FMA_S1B0N(a3xp, a2p, vkhp, s3p[0]);  // a3_q@k0
            PK_FMA_S1B1N(a3yp, a2p, vkhp, s3p[1]);  // a3_q@k1
            PK_FMA_S1B0(s3p[0], b2p, vkp);          // s3_q@k0 += b2_q*vk0
            PK_FMA_S1B1(s3p[1], b2p, vkp);          // s3_q@k1 += b2_q*vk1

            // level 4: 20 pk-FMAs (a3 broadcast from pair halves)
            #pragma unroll
            for (int i = 0; i < 5; ++i) {
                PK_FMA_B0(acc2[0][i], a3xp, vv2[i]);
                PK_FMA_B1(acc2[1][i], a3xp, vv2[i]);
                PK_FMA_B0(acc2[2][i], a3yp, vv2[i]);
                PK_FMA_B1(acc2[3][i], a3yp, vv2[i]);
            }
            s1a += via;
        }
    }

    // ---- Epilogue: signed single-path row ----
    if (store_mode) {
        float* row = ws + (size_t)bp * DTOT;
        if (tid < D1)
            row[tid] = sgn * (path[(T_LEN - 1) * C_DIM + tid] - path[tid]);
        if (tid < 50) {       // k0 == 0 threads own ij0 = 2*tid
            row[D1 + ij0]     = sgn * s2p[0];
            row[D1 + ij0 + 1] = sgn * s2p[1];
        }
        if (tid < 250) {
            #pragma unroll
            for (int ch = 0; ch < 2; ++ch) {          // ch=0 -> k0, ch=1 -> k0+5
                const int kk = k0 + 5 * ch;
                #pragma unroll
                for (int q = 0; q < 2; ++q) {
                    const int idx3 = (ij0 + q) * 10 + kk;
                    row[D1 + D2 + idx3] = sgn * s3p[ch][q];
                    float* p4 = row + D1 + D2 + D3 + (size_t)idx3 * 10;
                    #pragma unroll
                    for (int i = 0; i < 5; ++i)
                        *(f32x2*)&p4[2 * i] = sgn * acc2[ch * 2 + q][i];
                }
            }
        }
    } else {
        float* base = ws + (size_t)(b % nrep) * DTOT;
        if (tid < D1)
            atomicAdd(&base[tid],
                      sgn * (path[(T_LEN - 1) * C_DIM + tid] - path[tid]));
        if (tid < 50) {
            atomicAdd(&base[D1 + ij0],     sgn * s2p[0]);
            atomicAdd(&base[D1 + ij0 + 1], sgn * s2p[1]);
        }
        if (tid < 250) {
            #pragma unroll
            for (int ch = 0; ch < 2; ++ch) {
                const int kk = k0 + 5 * ch;
                #pragma unroll
                for (int q = 0; q < 2; ++q) {
                    const int idx3 = (ij0 + q) * 10 + kk;
                    atomicAdd(&base[D1 + D2 + idx3], sgn * s3p[ch][q]);
                    #pragma unroll
                    for (int l = 0; l < 10; ++l)
                        atomicAdd(&base[D1 + D2 + D3 + idx3 * 10 + l],
                                  sgn * acc2[ch * 2 + q][l >> 1][l & 1]);
                }
            }
        }
    }
}

// Fused stage 1+2, fence-free: each block sums 32 rows for a float2 d-tile
// (coalesced) into accvec via atomics; __syncthreads() drains vmcnt(0) so the
// adds are complete at the coherence point before thread 0 bumps the counter.
// The LAST block re-reads accvec via atomic-reads and writes the norm.
// Grid: (ceil(5555/256), nrows/32). No __threadfence anywhere.
__global__ __launch_bounds__(256) void sig_sumred_kernel(
    const float* __restrict__ ws, float* __restrict__ accvec,
    unsigned int* __restrict__ counter, float* __restrict__ out, int nblocks)
{
    const int d2 = blockIdx.x * 256 + threadIdx.x;   // DTOT/2 = 5555
    if (d2 < DTOT / 2) {
        const float* p = ws + (size_t)(blockIdx.y * 32) * DTOT + 2 * d2;
        float sx = 0.0f, sy = 0.0f;
        #pragma unroll
        for (int r = 0; r < 32; ++r) {
            const float2 v = *(const float2*)(p + (size_t)r * DTOT);
            sx += v.x; sy += v.y;
        }
        atomicAdd(&accvec[2 * d2], sx);
        atomicAdd(&accvec[2 * d2 + 1], sy);
    }

    __shared__ unsigned int lastflag;
    __syncthreads();   // drains this block's atomics (vmcnt 0 before barrier)
    if (threadIdx.x == 0)
        lastflag = (atomicAdd(counter, 1u) == (unsigned int)(nblocks - 1));
    __syncthreads();
    if (!lastflag) return;

    // Last block: all prior blocks' atomics are complete (each bumped the
    // counter only after its own barrier-drain). Atomic-reads bypass L1.
    float s = 0.0f;
    for (int d = (int)threadIdx.x; d < DTOT; d += 256) {
        const float v = atomicAdd(&accvec[d], 0.0f);
        s = fmaf(v, v, s);
    }
    for (int off = 32; off > 0; off >>= 1) s += __shfl_down(s, off, 64);
    __shared__ float red[4];
    if ((threadIdx.x & 63) == 0) red[threadIdx.x >> 6] = s;
    __syncthreads();
    if (threadIdx.x == 0)
        out[0] = sqrtf(red[0] + red[1] + red[2] + red[3]) * (1.0f / (float)BSZ);
}

// Fallback reduce for small-ws atomic-replica modes.
__global__ __launch_bounds__(256) void sig_reduce_kernel(
    const float* __restrict__ ws, int nrows, float* __restrict__ sumsq,
    unsigned int* __restrict__ counter, float* __restrict__ out, int nblocks)
{
    const int d = blockIdx.x * 256 + threadIdx.x;
    float s = 0.0f;
    if (d < DTOT) {
        for (int r = 0; r < nrows; ++r) s += ws[(size_t)r * DTOT + d];
        s = s * s;
    }
    for (int off = 32; off > 0; off >>= 1) s += __shfl_down(s, off, 64);
    __shared__ float red[4];
    __shared__ unsigned int lastflag;
    if ((threadIdx.x & 63) == 0) red[threadIdx.x >> 6] = s;
    __syncthreads();
    if (threadIdx.x == 0) {
        atomicAdd(sumsq, red[0] + red[1] + red[2] + red[3]);
        __threadfence();
        lastflag = (atomicAdd(counter, 1u) == (unsigned int)(nblocks - 1));
    }
    __syncthreads();
    if (threadIdx.x == 0 && lastflag) {
        __threadfence();
        out[0] = sqrtf(*(volatile float*)sumsq) * (1.0f / (float)BSZ);
    }
}

extern "C" void kernel_launch(void* const* d_in, const int* in_sizes, int n_in,
                              void* d_out, int out_size, void* d_ws, size_t ws_size,
                              hipStream_t stream) {
    const float* original   = (const float*)d_in[0];
    const float* generated  = (const float*)d_in[1];
    const int*   sample_idx = (const int*)d_in[2];
    float* out = (float*)d_out;
    float* ws  = (float*)d_ws;

    // Layouts:
    //  split: rows [0, 2N*DTOT), accvec [+DTOT), pad [+1), counter [+1)
    //  store: rows [0, N*DTOT),  accvec [+DTOT), pad [+1), counter [+1)
    const size_t need_split = ((size_t)(2 * NPAIR + 1) * DTOT + 2) * sizeof(float);
    const size_t need_store = ((size_t)(NPAIR + 1) * DTOT + 2) * sizeof(float);

    if (ws_size >= need_split) {
        // Primary: 2 dispatches. accum block 0 zero-inits accvec+pad+counter;
        // fence-free fused sum+norm finishes.
        float* accvec = ws + (size_t)2 * NPAIR * DTOT;
        unsigned int* counter = (unsigned int*)(accvec + DTOT + 1);
        sig_accum_kernel<<<2 * NPAIR, 256, 0, stream>>>(original, generated,
                                                        sample_idx, ws, accvec,
                                                        1, 1);
        dim3 g1((DTOT / 2 + 255) / 256, 2 * NPAIR / 32);
        sig_sumred_kernel<<<g1, 256, 0, stream>>>(ws, accvec, counter, out,
                                                  (int)(g1.x * g1.y));
    } else if (ws_size >= need_store) {
        // Pair-atomic rows + fused reduction.
        float* accvec = ws + (size_t)NPAIR * DTOT;
        unsigned int* counter = (unsigned int*)(accvec + DTOT + 1);
        hipMemsetAsync(ws, 0, need_store, stream);
        sig_accum_kernel<<<2 * NPAIR, 256, 0, stream>>>(original, generated,
                                                        sample_idx, ws, nullptr,
                                                        NPAIR, 0);
        dim3 g1((DTOT / 2 + 255) / 256, NPAIR / 32);
        sig_sumred_kernel<<<g1, 256, 0, stream>>>(ws, accvec, counter, out,
                                                  (int)(g1.x * g1.y));
    } else {
        int nrep = 1;
        if (ws_size >= ((size_t)64 * DTOT + 2) * sizeof(float)) nrep = 64;
        else if (ws_size >= ((size_t)8 * DTOT + 2) * sizeof(float)) nrep = 8;
        float* sumsq = ws + (size_t)nrep * DTOT;
        unsigned int* counter = (unsigned int*)(sumsq + 1);
        hipMemsetAsync(ws, 0, ((size_t)nrep * DTOT + 2) * sizeof(float), stream);
        sig_accum_kernel<<<2 * NPAIR, 256, 0, stream>>>(original, generated,
                                                        sample_idx, ws, nullptr,
                                                        nrep, 0);
        const int nb2 = (DTOT + 255) / 256;
        sig_reduce_kernel<<<nb2, 256, 0, stream>>>(ws, nrep, sumsq, counter, out, nb2);
    }
}

// Round 11
// 279.695 us; speedup vs baseline: 4.2139x; 1.0796x over previous
//
#include <hip/hip_runtime.h>

// SigWassersteinMetric: depth-4 path signature, C=10, T=256.
//   original: (4096, 256, 10) f32; generated: (1024, 256, 10) f32; sample_idx: (1024,)
//
// ROUND-25: best accum (R24: R17 loop, 256thr, block0-init, 190us) +
// best reduction (R22: separate fence-light sum + sumsq, residual 79us).
//   - R24 post-mortem: fused sumred REGRESSED (residual 112us vs R22's 79):
//     the single-block serial tail (11110 L2 atomic-reads) + straggler wait
//     costs more than the dispatch boundary it saved. Lesson: launch-fusion
//     only pays when the fused tail is parallel.
//   - R22 ran the slower 128-thread accum (200us); R24 the better accum with
//     the worse reduction. This round combines the winners:
//       accum (store rows, block0 zero-inits accvec+sumsq+counter)
//       sig_sum_kernel   (1408 blocks, 91MB coalesced reads, accvec atomics)
//       sig_sumsq_kernel (44 blocks, fences only in 44 threads)
//   - Prediction: accum ~190 unchanged; total 266-275.
//
// Horner-factored Chen step (verified rounds 2/4-13):
//   A2 = S2 + (S1 + v/4) (x) v/3 ;  B2 = S2 + (S1 + v/3) (x) v/2
//   A3 = S3 + A2 (x) v/2 ;  S4' = S4 + A3 (x) v ;  S3' = S3 + B2 (x) v
//   S2' = S2 + (S1 + v/2) (x) v ;  S1 closed-form in epilogue.
#define T_LEN 256
#define C_DIM 10
#define NSTEP 255
#define BSZ   1024
#define NPAIR 1024
#define D1 10
#define D2 100
#define D3 1000
#define DTOT 11110
#define PATH_ELEMS (T_LEN * C_DIM)   // 2560
#define DX_ELEMS (NSTEP * C_DIM)     // 2550
#define DXROW 12                     // padded dx row stride (48 B, 16B-aligned)

typedef float f32x2 __attribute__((ext_vector_type(2)));
typedef float f32x4 __attribute__((ext_vector_type(4)));

// d += bcast(a.lo) * b
#define PK_FMA_B0(d, a, b) \
    asm("v_pk_fma_f32 %0, %1, %2, %0 op_sel:[0,0,0] op_sel_hi:[0,1,1]" \
        : "+v"(d) : "v"(a), "v"(b))
// d += bcast(a.hi) * b
#define PK_FMA_B1(d, a, b) \
    asm("v_pk_fma_f32 %0, %1, %2, %0 op_sel:[1,0,0] op_sel_hi:[1,1,1]" \
        : "+v"(d) : "v"(a), "v"(b))
// d = bcast(a.lo) * b + c
#define PK_FMA_B0N(d, a, b, c) \
    asm("v_pk_fma_f32 %0, %1, %2, %3 op_sel:[0,0,0] op_sel_hi:[0,1,1]" \
        : "=v"(d) : "v"(a), "v"(b), "v"(c))
// d = bcast(a.hi) * b + c
#define PK_FMA_B1N(d, a, b, c) \
    asm("v_pk_fma_f32 %0, %1, %2, %3 op_sel:[1,0,0] op_sel_hi:[1,1,1]" \
        : "=v"(d) : "v"(a), "v"(b), "v"(c))
// d = a * bcast(b.lo) + c   (src1 broadcast)
#define PK_FMA_S1B0N(d, a, b, c) \
    asm("v_pk_fma_f32 %0, %1, %2, %3 op_sel:[0,0,0] op_sel_hi:[1,0,1]" \
        : "=v"(d) : "v"(a), "v"(b), "v"(c))
// d = a * bcast(b.hi) + c
#define PK_FMA_S1B1N(d, a, b, c) \
    asm("v_pk_fma_f32 %0, %1, %2, %3 op_sel:[0,1,0] op_sel_hi:[1,1,1]" \
        : "=v"(d) : "v"(a), "v"(b), "v"(c))
// d += a * bcast(b.lo)
#define PK_FMA_S1B0(d, a, b) \
    asm("v_pk_fma_f32 %0, %1, %2, %0 op_sel:[0,0,0] op_sel_hi:[1,0,1]" \
        : "+v"(d) : "v"(a), "v"(b))
// d += a * bcast(b.hi)
#define PK_FMA_S1B1(d, a, b) \
    asm("v_pk_fma_f32 %0, %1, %2, %0 op_sel:[0,1,0] op_sel_hi:[1,1,1]" \
        : "+v"(d) : "v"(a), "v"(b))
// d = a * 0.5 (both halves)
#define PK_MUL_HALF(d, a) \
    asm("v_pk_mul_f32 %0, %1, 0.5 op_sel:[0,0] op_sel_hi:[1,0]" \
        : "=v"(d) : "v"(a))

__global__ __launch_bounds__(256)
void sig_accum_kernel(
    const float* __restrict__ original,
    const float* __restrict__ generated,
    const int* __restrict__ sample_idx,
    float* __restrict__ ws,
    float* __restrict__ accinit,   // non-null: block 0 zeroes DTOT+2 floats
    int nrep, int store_mode)
{
    const int tid  = threadIdx.x;
    const int bp   = blockIdx.x;         // 0 .. 2*NPAIR-1
    const int b    = bp >> 1;            // pair index
    const int pass = bp & 1;             // 0 = generated (-), 1 = original (+)
    const float sgn = pass ? 1.0f : -1.0f;

    __shared__ __align__(16) float s_dx[NSTEP * DXROW];  // 12240 B

    if (accinit != nullptr && bp == 0) {
        for (int i = tid; i < DTOT + 2; i += 256) accinit[i] = 0.0f;
    }

    const float* path = pass
        ? original + (size_t)sample_idx[b] * PATH_ELEMS
        : generated + (size_t)b * PATH_ELEMS;

    for (int idx = tid; idx < DX_ELEMS; idx += 256) {
        int t = idx / C_DIM, c = idx - t * C_DIM;
        s_dx[t * DXROW + c] = path[idx + C_DIM] - path[idx];
    }
    __syncthreads();

    const int mbase = 2 * tid;               // valid tid<250
    const int k0  = mbase / 100;             // 0..4
    const int ij0 = mbase - k0 * 100;        // even
    const int ia  = ij0 / 10;
    const int j0  = ij0 - ia * 10;           // even -> (j0, j0+1) same decade

    float s1a = 0.0f;
    f32x2 s2p = {0.0f, 0.0f};                 // (q0, q1)
    f32x2 s3p[2] = {{0.0f, 0.0f}, {0.0f, 0.0f}};  // [0]=(q0,q1)@k0, [1]=@k1
    f32x2 acc2[4][5];                         // [0]=q0k0 [1]=q1k0 [2]=q0k1 [3]=q1k1
    #pragma unroll
    for (int r = 0; r < 4; ++r)
        #pragma unroll
        for (int i = 0; i < 5; ++i) acc2[r][i] = (f32x2){0.0f, 0.0f};

    if (tid < 250) {
        const float* vrow = s_dx;
        #pragma unroll 2
        for (int t = 0; t < NSTEP; ++t, vrow += DXROW) {
            const f32x4 va = *(const f32x4*)(vrow);        // v0..v3 (uniform)
            const f32x4 vb = *(const f32x4*)(vrow + 4);    // v4..v7 (uniform)
            const f32x2 vc = *(const f32x2*)(vrow + 8);    // v8,v9  (uniform)
            const f32x2 vjp = *(const f32x2*)(vrow + j0);  // vj for q0,q1
            const float via = vrow[ia];
            f32x2 vkp;
            vkp.x = vrow[k0];
            vkp.y = vrow[k0 + 5];

            const f32x2 vv2[5] = {va.xy, va.zw, vb.xy, vb.zw, vc};

            // scalar prefix terms
            const float t3  = fmaf(via, 0.5f, s1a);
            const float t1b = fmaf(via, 0.25f, s1a) * (1.0f / 3.0f);
            const float t2b = fmaf(via, (1.0f / 3.0f), s1a) * 0.5f;
            f32x2 pA; pA.x = t1b; pA.y = t2b;
            f32x2 pT; pT.x = t3;  pT.y = t3;

            f32x2 vkhp;                       // (vk0*0.5, vk1*0.5)
            PK_MUL_HALF(vkhp, vkp);

            // level 2 (q-pairs)
            f32x2 a2p, b2p;
            PK_FMA_B0N(a2p, pA, vjp, s2p);    // a2_q = t1b*vj_q + s2_q
            PK_FMA_B1N(b2p, pA, vjp, s2p);    // b2_q = t2b*vj_q + s2_q
            PK_FMA_B0(s2p, pT, vjp);          // s2_q += t3*vj_q

            // level 3 (q-pairs, k-channel broadcast from vkp/vkhp halves)
            f32x2 a3xp, a3yp;
            PK_FMA_S1B0N(a3xp, a2p, vkhp, s3p[0]);  // a3_q@k0
            PK_FMA_S1B1N(a3yp, a2p, vkhp, s3p[1]);  // a3_q@k1
            PK_FMA_S1B0(s3p[0], b2p, vkp);          // s3_q@k0 += b2_q*vk0
            PK_FMA_S1B1(s3p[1], b2p, vkp);          // s3_q@k1 += b2_q*vk1

            // level 4: 20 pk-FMAs (a3 broadcast from pair halves)
            #pragma unroll
            for (int i = 0; i < 5; ++i) {
                PK_FMA_B0(acc2[0][i], a3xp, vv2[i]);
                PK_FMA_B1(acc2[1][i], a3xp, vv2[i]);
                PK_FMA_B0(acc2[2][i], a3yp, vv2[i]);
                PK_FMA_B1(acc2[3][i], a3yp, vv2[i]);
            }
            s1a += via;
        }
    }

    // ---- Epilogue: signed single-path row ----
    if (store_mode) {
        float* row = ws + (size_t)bp * DTOT;
        if (tid < D1)
            row[tid] = sgn * (path[(T_LEN - 1) * C_DIM + tid] - path[tid]);
        if (tid < 50) {       // k0 == 0 threads own ij0 = 2*tid
            row[D1 + ij0]     = sgn * s2p[0];
            row[D1 + ij0 + 1] = sgn * s2p[1];
        }
        if (tid < 250) {
            #pragma unroll
            for (int ch = 0; ch < 2; ++ch) {          // ch=0 -> k0, ch=1 -> k0+5
                const int kk = k0 + 5 * ch;
                #pragma unroll
                for (int q = 0; q < 2; ++q) {
                    const int idx3 = (ij0 + q) * 10 + kk;
                    row[D1 + D2 + idx3] = sgn * s3p[ch][q];
                    float* p4 = row + D1 + D2 + D3 + (size_t)idx3 * 10;
                    #pragma unroll
                    for (int i = 0; i < 5; ++i)
                        *(f32x2*)&p4[2 * i] = sgn * acc2[ch * 2 + q][i];
                }
            }
        }
    } else {
        float* base = ws + (size_t)(b % nrep) * DTOT;
        if (tid < D1)
            atomicAdd(&base[tid],
                      sgn * (path[(T_LEN - 1) * C_DIM + tid] - path[tid]));
        if (tid < 50) {
            atomicAdd(&base[D1 + ij0],     sgn * s2p[0]);
            atomicAdd(&base[D1 + ij0 + 1], sgn * s2p[1]);
        }
        if (tid < 250) {
            #pragma unroll
            for (int ch = 0; ch < 2; ++ch) {
                const int kk = k0 + 5 * ch;
                #pragma unroll
                for (int q = 0; q < 2; ++q) {
                    const int idx3 = (ij0 + q) * 10 + kk;
                    atomicAdd(&base[D1 + D2 + idx3], sgn * s3p[ch][q]);
                    #pragma unroll
                    for (int l = 0; l < 10; ++l)
                        atomicAdd(&base[D1 + D2 + D3 + idx3 * 10 + l],
                                  sgn * acc2[ch * 2 + q][l >> 1][l & 1]);
                }
            }
        }
    }
}

// Stage 1: block sums 32 rows for a float2 d-tile (coalesced), atomically
// accumulates into accvec[DTOT]. Grid: (ceil(5555/256), nrows/32). NO fences.
__global__ __launch_bounds__(256) void sig_sum_kernel(
    const float* __restrict__ ws, float* __restrict__ accvec)
{
    const int d2 = blockIdx.x * 256 + threadIdx.x;   // DTOT/2 = 5555
    if (d2 >= DTOT / 2) return;
    const float* p = ws + (size_t)(blockIdx.y * 32) * DTOT + 2 * d2;
    float sx = 0.0f, sy = 0.0f;
    #pragma unroll
    for (int r = 0; r < 32; ++r) {
        const float2 v = *(const float2*)(p + (size_t)r * DTOT);
        sx += v.x; sy += v.y;
    }
    atomicAdd(&accvec[2 * d2], sx);
    atomicAdd(&accvec[2 * d2 + 1], sy);
}

// Stage 2: sum of squares -> sumsq; last block writes the norm.
__global__ __launch_bounds__(256) void sig_sumsq_kernel(
    const float* __restrict__ accvec, float* __restrict__ sumsq,
    unsigned int* __restrict__ counter, float* __restrict__ out, int nblocks)
{
    const int d = blockIdx.x * 256 + threadIdx.x;
    float s = 0.0f;
    if (d < DTOT) { float v = accvec[d]; s = v * v; }
    for (int off = 32; off > 0; off >>= 1) s += __shfl_down(s, off, 64);
    __shared__ float red[4];
    __shared__ unsigned int lastflag;
    if ((threadIdx.x & 63) == 0) red[threadIdx.x >> 6] = s;
    __syncthreads();
    if (threadIdx.x == 0) {
        atomicAdd(sumsq, red[0] + red[1] + red[2] + red[3]);
        __threadfence();
        lastflag = (atomicAdd(counter, 1u) == (unsigned int)(nblocks - 1));
    }
    __syncthreads();
    if (threadIdx.x == 0 && lastflag) {
        __threadfence();
        out[0] = sqrtf(*(volatile float*)sumsq) * (1.0f / (float)BSZ);
    }
}

// Fallback reduce for small-ws atomic-replica modes.
__global__ __launch_bounds__(256) void sig_reduce_kernel(
    const float* __restrict__ ws, int nrows, float* __restrict__ sumsq,
    unsigned int* __restrict__ counter, float* __restrict__ out, int nblocks)
{
    const int d = blockIdx.x * 256 + threadIdx.x;
    float s = 0.0f;
    if (d < DTOT) {
        for (int r = 0; r < nrows; ++r) s += ws[(size_t)r * DTOT + d];
        s = s * s;
    }
    for (int off = 32; off > 0; off >>= 1) s += __shfl_down(s, off, 64);
    __shared__ float red[4];
    __shared__ unsigned int lastflag;
    if ((threadIdx.x & 63) == 0) red[threadIdx.x >> 6] = s;
    __syncthreads();
    if (threadIdx.x == 0) {
        atomicAdd(sumsq, red[0] + red[1] + red[2] + red[3]);
        __threadfence();
        lastflag = (atomicAdd(counter, 1u) == (unsigned int)(nblocks - 1));
    }
    __syncthreads();
    if (threadIdx.x == 0 && lastflag) {
        __threadfence();
        out[0] = sqrtf(*(volatile float*)sumsq) * (1.0f / (float)BSZ);
    }
}

extern "C" void kernel_launch(void* const* d_in, const int* in_sizes, int n_in,
                              void* d_out, int out_size, void* d_ws, size_t ws_size,
                              hipStream_t stream) {
    const float* original   = (const float*)d_in[0];
    const float* generated  = (const float*)d_in[1];
    const int*   sample_idx = (const int*)d_in[2];
    float* out = (float*)d_out;
    float* ws  = (float*)d_ws;

    // Layouts:
    //  split: rows [0, 2N*DTOT), accvec [+DTOT), sumsq [+1), counter [+1)
    //  store: rows [0, N*DTOT),  accvec [+DTOT), sumsq [+1), counter [+1)
    const size_t need_split = ((size_t)(2 * NPAIR + 1) * DTOT + 2) * sizeof(float);
    const size_t need_store = ((size_t)(NPAIR + 1) * DTOT + 2) * sizeof(float);

    if (ws_size >= need_split) {
        // Primary: 3 dispatches. accum block 0 zero-inits accvec+sumsq+counter.
        float* accvec = ws + (size_t)2 * NPAIR * DTOT;
        float* sumsq  = accvec + DTOT;
        unsigned int* counter = (unsigned int*)(sumsq + 1);
        sig_accum_kernel<<<2 * NPAIR, 256, 0, stream>>>(original, generated,
                                                        sample_idx, ws, accvec,
                                                        1, 1);
        dim3 g1((DTOT / 2 + 255) / 256, 2 * NPAIR / 32);
        sig_sum_kernel<<<g1, 256, 0, stream>>>(ws, accvec);
        const int nb2 = (DTOT + 255) / 256;
        sig_sumsq_kernel<<<nb2, 256, 0, stream>>>(accvec, sumsq, counter, out, nb2);
    } else if (ws_size >= need_store) {
        // Pair-atomic rows + separate reduction.
        float* accvec = ws + (size_t)NPAIR * DTOT;
        float* sumsq  = accvec + DTOT;
        unsigned int* counter = (unsigned int*)(sumsq + 1);
        hipMemsetAsync(ws, 0, need_store, stream);
        sig_accum_kernel<<<2 * NPAIR, 256, 0, stream>>>(original, generated,
                                                        sample_idx, ws, nullptr,
                                                        NPAIR, 0);
        dim3 g1((DTOT / 2 + 255) / 256, NPAIR / 32);
        sig_sum_kernel<<<g1, 256, 0, stream>>>(ws, accvec);
        const int nb2 = (DTOT + 255) / 256;
        sig_sumsq_kernel<<<nb2, 256, 0, stream>>>(accvec, sumsq, counter, out, nb2);
    } else {
        int nrep = 1;
        if (ws_size >= ((size_t)64 * DTOT + 2) * sizeof(float)) nrep = 64;
        else if (ws_size >= ((size_t)8 * DTOT + 2) * sizeof(float)) nrep = 8;
        float* sumsq = ws + (size_t)nrep * DTOT;
        unsigned int* counter = (unsigned int*)(sumsq + 1);
        hipMemsetAsync(ws, 0, ((size_t)nrep * DTOT + 2) * sizeof(float), stream);
        sig_accum_kernel<<<2 * NPAIR, 256, 0, stream>>>(original, generated,
                                                        sample_idx, ws, nullptr,
                                                        nrep, 0);
        const int nb2 = (DTOT + 255) / 256;
        sig_reduce_kernel<<<nb2, 256, 0, stream>>>(ws, nrep, sumsq, counter, out, nb2);
    }
}